// Round 5
// baseline (494.725 us; speedup 1.0000x reference)
//
#include <hip/hip_runtime.h>

// Problem constants: B=1024, L=64, N=65536, V=100000, E=300, RH=M=50, NC=3
// tree: balanced binary, parent=(i-1)//2, depths 0..6, locs 0..31 have children

typedef __attribute__((ext_vector_type(8))) short bf16x8;
typedef __attribute__((ext_vector_type(4))) float f32x4;

// ---- activations ----
__device__ __forceinline__ float fsig(float x) { return 1.0f / (1.0f + __expf(-x)); }
__device__ __forceinline__ float ftanh(float x) {
    float a = fabsf(x);
    float t = __expf(2.0f * a);
    float r = 1.0f - 2.0f / (t + 1.0f);
    return copysignf(r, x);
}
__device__ __forceinline__ float fsig2(float x) {
    float e = __builtin_amdgcn_exp2f(-1.4426950408889634f * x);
    return __builtin_amdgcn_rcpf(1.0f + e);
}
__device__ __forceinline__ float ftanh2(float x) {
    float e = __builtin_amdgcn_exp2f(2.8853900817779268f * x);
    return 1.0f - 2.0f * __builtin_amdgcn_rcpf(1.0f + e);
}

// round-to-nearest-even f32 -> bf16 (returns upper 16 bits)
__device__ __forceinline__ unsigned short rne_bf16(float f) {
    unsigned u = __builtin_bit_cast(unsigned, f);
    unsigned r = u + 0x7fffu + ((u >> 16) & 1u);
    return (unsigned short)(r >> 16);
}
// fp32 -> bf16 hi + bf16 lo (RNE both limbs; combined residual ~2^-17 rel, unbiased)
__device__ __forceinline__ void split2(float f, unsigned short& h, unsigned short& l) {
    h = rne_bf16(f);
    float fh = __builtin_bit_cast(float, ((unsigned)h) << 16);
    float r = f - fh;   // exact (Sterbenz)
    l = rne_bf16(r);
}

__device__ __forceinline__ void async_lds16(const void* g, void* l) {
    __builtin_amdgcn_global_load_lds(
        (const __attribute__((address_space(1))) unsigned int*)g,
        (__attribute__((address_space(3))) unsigned int*)l, 16, 0, 0);
}

__device__ __forceinline__ bf16x8 pack8(const unsigned short* h) {
    bf16x8 v;
    #pragma unroll
    for (int e = 0; e < 8; ++e) v[e] = (short)h[e];
    return v;
}

// ---------------------------------------------------------------------------
// K0: convert weights [B1;B2] (rows = output cols, K contraction) to chunked
// hi|lo bf16 layout: out[(((c*2+h)*4 + kq)*BN + n)*8 + e] covers
// k = c*32 + kq*8 + e.  n >= Rreal or k >= K zero-filled.
// Lane-consecutive for direct global frag reads (L2-resident).
// Total size per call: KCH*2*4*BN*8 shorts.
// ---------------------------------------------------------------------------
__global__ void conv_kernel(const float* __restrict__ B1, const float* __restrict__ B2,
                            int split, int K, int Rreal, int BN, int KCH,
                            unsigned short* __restrict__ out) {
    int q = blockIdx.x * 256 + threadIdx.x;
    int total = KCH * 4 * BN;
    if (q >= total) return;
    int n  = q % BN;
    int kq = (q / BN) & 3;
    int c  = q / (BN * 4);
    const float* row = (n < split) ? (B1 + (size_t)n * K) : (B2 + (size_t)(n - split) * K);
    unsigned short h[8], l[8];
    #pragma unroll
    for (int e = 0; e < 8; ++e) {
        int k = c * 32 + kq * 8 + e;
        float v = (n < Rreal && k < K) ? row[k] : 0.0f;
        split2(v, h[e], l[e]);
    }
    size_t hb = ((((size_t)c * 2 + 0) * 4 + kq) * BN + n) * 8;
    size_t lb = ((((size_t)c * 2 + 1) * 4 + kq) * BN + n) * 8;
    *(ushort4*)&out[hb]     = make_ushort4(h[0], h[1], h[2], h[3]);
    *(ushort4*)&out[hb + 4] = make_ushort4(h[4], h[5], h[6], h[7]);
    *(ushort4*)&out[lb]     = make_ushort4(l[0], l[1], l[2], l[3]);
    *(ushort4*)&out[lb + 4] = make_ushort4(l[4], l[5], l[6], l[7]);
}

// ---------------------------------------------------------------------------
// Split-bf16 MFMA GEMM, "direct" form: ZERO LDS, ZERO barriers.
// Rationale (rocprof, K1 @97us): 64KB LDS capped occupancy at 2 blocks/CU and
// the per-chunk __syncthreads drained the just-issued B-staging DMAs; neither
// operand actually needs LDS: B (573KB pre-converted weight) is L2-resident
// and read coalesced per-wave; the A hi/lo frags are identical across the 4
// waves, so each wave gathers its own 4 rows x 32B per lane per chunk and
// splits to bf16 hi/lo IN-REGISTER (VALU overlaps MFMA pipe).  Each wave
// free-runs its own pipeline with A prefetched one chunk ahead.
// acc 4x(BN/64) f32x4 per lane; 3 mfma terms: Ah*Bh + Al*Bh + Ah*Bl.
// ---------------------------------------------------------------------------
template<int BN, int KCH, int KREAL, int NCOLS, bool GATHER>
__global__ __launch_bounds__(256, 2)
void gemm_split(const float* __restrict__ A, const int* __restrict__ ids,
                const unsigned short* __restrict__ Bc,
                const float* __restrict__ bias1, const float* __restrict__ bias2,
                int split, float* __restrict__ C) {
    constexpr int NTW = BN / 64;   // 16-col tiles per wave
    const int tid = threadIdx.x;
    const int m0 = blockIdx.x * 64;
    const int w = tid >> 6, lane = tid & 63;
    const int r16 = lane & 15, quad = lane >> 4;
    const int wn = w * (BN / 4);

    // this lane's A rows: i*16 + r16 (same across waves; quad picks k-slice)
    const float* arow[4];
    #pragma unroll
    for (int i = 0; i < 4; ++i) {
        int m = i * 16 + r16;
        arow[i] = GATHER ? (A + (size_t)ids[m0 + m] * KREAL)
                         : (A + (size_t)(m0 + m) * KREAL);
    }

    float ar[4][8];
    auto loadA = [&](int c) {
        const int k0 = c * 32 + quad * 8;
        #pragma unroll
        for (int i = 0; i < 4; ++i) {
            if (k0 + 8 <= KREAL) {
                float4 p = *(const float4*)(arow[i] + k0);
                float4 q = *(const float4*)(arow[i] + k0 + 4);
                ar[i][0]=p.x; ar[i][1]=p.y; ar[i][2]=p.z; ar[i][3]=p.w;
                ar[i][4]=q.x; ar[i][5]=q.y; ar[i][6]=q.z; ar[i][7]=q.w;
            } else {
                #pragma unroll
                for (int e = 0; e < 8; ++e)
                    ar[i][e] = (k0 + e < KREAL) ? arow[i][k0 + e] : 0.0f;
            }
        }
    };

    f32x4 acc[4][NTW] = {};
    loadA(0);

    #pragma unroll 1
    for (int c = 0; c < KCH; ++c) {
        // split current chunk's A to bf16 hi/lo frags (frees ar for prefetch)
        bf16x8 ah[4], al[4];
        #pragma unroll
        for (int i = 0; i < 4; ++i) {
            unsigned short hh[8], ll[8];
            #pragma unroll
            for (int e = 0; e < 8; ++e) split2(ar[i][e], hh[e], ll[e]);
            ah[i] = pack8(hh);
            al[i] = pack8(ll);
        }
        if (c + 1 < KCH) loadA(c + 1);   // prefetch next chunk's A

        const unsigned short* bh_base = Bc + (size_t)((c * 2 + 0) * 4 + quad) * BN * 8;
        const unsigned short* bl_base = Bc + (size_t)((c * 2 + 1) * 4 + quad) * BN * 8;
        #pragma unroll
        for (int t = 0; t < NTW; ++t) {
            int n = wn + t * 16 + r16;
            bf16x8 bh = *(const bf16x8*)&bh_base[(size_t)n * 8];
            bf16x8 bl = *(const bf16x8*)&bl_base[(size_t)n * 8];
            #pragma unroll
            for (int i = 0; i < 4; ++i) {
                acc[i][t] = __builtin_amdgcn_mfma_f32_16x16x32_bf16(ah[i], bh, acc[i][t], 0, 0, 0);
                acc[i][t] = __builtin_amdgcn_mfma_f32_16x16x32_bf16(al[i], bh, acc[i][t], 0, 0, 0);
                acc[i][t] = __builtin_amdgcn_mfma_f32_16x16x32_bf16(ah[i], bl, acc[i][t], 0, 0, 0);
            }
        }
    }

    #pragma unroll
    for (int t = 0; t < NTW; ++t) {
        int ncol = wn + t * 16 + r16;
        if (ncol < NCOLS) {
            float bv = (ncol < split) ? bias1[ncol] : bias2[ncol - split];
            #pragma unroll
            for (int i = 0; i < 4; ++i)
                #pragma unroll
                for (int r = 0; r < 4; ++r) {
                    int mrow = m0 + i * 16 + quad * 4 + r;
                    C[(size_t)mrow * NCOLS + ncol] = acc[i][t][r] + bv;
                }
        }
    }
}

// ---------------------------------------------------------------------------
// K2: MFMA-batched BiLSTM. Block = (dir, 16 sentences), 256 thr = 4 waves.
// M=16 rows = sentences; N=200 gates = 13 tiles split 4/3/3/3 per wave;
// K=50 padded 64 (2 chunks), split-bf16 3-term. W_hh frags register-resident.
// h round-trips LDS [kq][sent][8]; xg prefetched 2 steps ahead (ring of 3)
// via global_load_lds.
//
// Counted-vmcnt sync (T3/T4): per-wave VMEM instruction counts are UNIFORM —
// gate items are assigned q = w*200 + lane + 64*j (j=0..3, j=3 active for
// lane<8), so EVERY wave issues exactly 4 h-stores + 4 DMA loads per step.
// Audit at barrier #1 of step t (need L_t = P_{t-2} landed):
//   ops newer than P_{t-2}: S_{t-2}(4) + P_{t-1}(4) + S_{t-1}(4) + P_t(4)
//   = 16 for every wave -> s_waitcnt vmcnt(16) waits for exactly L_t.
// Stores are never waited on; prefetch loads stay in flight across both
// barriers.  Tail steps issue clamped dummy loads to keep the count uniform.
// Prologue __syncthreads() drains L_0, L_1 so steps 0..1 are trivially safe.
// ---------------------------------------------------------------------------
constexpr int WHC_DIR = 2 * 2 * 4 * 208 * 8;   // shorts per direction = 26624

__global__ __launch_bounds__(256)
void lstm_mfma(const float* __restrict__ xg, const unsigned short* __restrict__ Whc,
               float* __restrict__ x) {
    const int bi = blockIdx.x;
    const int dir = bi & 1;
    const int b0 = (bi >> 1) * 16;
    const int tid = threadIdx.x;
    const int w = tid >> 6, lane = tid & 63;
    const int r16 = lane & 15, quad = lane >> 4;

    __shared__ __align__(16) unsigned short Ah[8 * 16 * 8];  // [kq][s][8]
    __shared__ __align__(16) unsigned short Al[8 * 16 * 8];
    __shared__ __align__(16) float G[208 * 20];              // [gate][sent pad20]
    __shared__ __align__(16) float Xs[3][16][268];           // xg ring (lead 2)

    const int n0 = (w == 0) ? 0 : (w == 1) ? 4 : (w == 2) ? 7 : 10;
    const int nc = (w == 0) ? 4 : 3;

    const unsigned short* Wd = Whc + (size_t)dir * WHC_DIR;
    bf16x8 bfr[4][2][2];   // [tile][chunk][hi/lo]
    #pragma unroll
    for (int t = 0; t < 4; ++t) {
        int col = (n0 + ((t < nc) ? t : 0)) * 16 + r16;
        #pragma unroll
        for (int c = 0; c < 2; ++c)
            #pragma unroll
            for (int h = 0; h < 2; ++h)
                bfr[t][c][h] = *(const bf16x8*)&Wd[((((size_t)c * 2 + h) * 4 + quad) * 208 + col) * 8];
    }

    for (int q = tid; q < 512; q += 256) {
        ((unsigned*)Ah)[q] = 0u;
        ((unsigned*)Al)[q] = 0u;
    }

    // gate-item mapping: q = w*200 + lane + 64*j  (uniform 4 store instrs/wave)
    int ss[4], ms[4];
    bool act[4];
    #pragma unroll
    for (int j = 0; j < 4; ++j) {
        int q = w * 200 + lane + 64 * j;
        ss[j] = q & 15;
        ms[j] = q >> 4;
        act[j] = (lane + 64 * j) < 200;
    }
    float c_reg[4] = {0.0f, 0.0f, 0.0f, 0.0f};

    // prologue: steps 0 and 1 into ring slots 0,1 (drained by __syncthreads)
    #pragma unroll
    for (int p = 0; p < 2; ++p) {
        int idx0 = dir ? (63 - p) : p;
        #pragma unroll
        for (int i = 0; i < 4; ++i) {
            int s = w * 4 + i;
            const float* src = xg + ((size_t)(b0 + s) * 64 + idx0) * 400 + dir * 200 + lane * 4;
            async_lds16(src, &Xs[p][s][lane * 4]);
        }
    }
    __syncthreads();

    for (int step = 0; step < 64; ++step) {
        const int buf = step % 3;
        const int idx = dir ? (63 - step) : step;
        {
            // issue prefetch for step+2 (clamped dummy reload at the tail to
            // keep the per-step vmem instruction count uniform)
            int stepn = step + 2; if (stepn > 63) stepn = 63;
            const int slot = (step + 2) % 3;
            const int idxn = dir ? (63 - stepn) : stepn;
            #pragma unroll
            for (int i = 0; i < 4; ++i) {
                int s = w * 4 + i;
                const float* src = xg + ((size_t)(b0 + s) * 64 + idxn) * 400 + dir * 200 + lane * 4;
                async_lds16(src, &Xs[slot][s][lane * 4]);
            }
            __builtin_amdgcn_sched_barrier(0);   // pin issue before the counted wait
        }
        bf16x8 ah[2], al[2];
        #pragma unroll
        for (int c = 0; c < 2; ++c) {
            ah[c] = *(const bf16x8*)&Ah[((c * 4 + quad) * 16 + r16) * 8];
            al[c] = *(const bf16x8*)&Al[((c * 4 + quad) * 16 + r16) * 8];
        }
        f32x4 acc[4] = {};
        #pragma unroll
        for (int t = 0; t < 4; ++t) {
            if (t < nc) {
                #pragma unroll
                for (int c = 0; c < 2; ++c) {
                    acc[t] = __builtin_amdgcn_mfma_f32_16x16x32_bf16(ah[c], bfr[t][c][0], acc[t], 0, 0, 0);
                    acc[t] = __builtin_amdgcn_mfma_f32_16x16x32_bf16(al[c], bfr[t][c][0], acc[t], 0, 0, 0);
                    acc[t] = __builtin_amdgcn_mfma_f32_16x16x32_bf16(ah[c], bfr[t][c][1], acc[t], 0, 0, 0);
                }
            }
        }
        #pragma unroll
        for (int t = 0; t < 4; ++t) {
            if (t < nc) {
                int col = (n0 + t) * 16 + r16;
                *(f32x4*)&G[col * 20 + quad * 4] = acc[t];
            }
        }
        // barrier #1: G visible to all waves; own L_t landed via counted
        // vmcnt(16) (exact for every wave — uniform instruction counts);
        // cross-wave Xs coverage comes from the barrier itself.
        asm volatile("s_waitcnt lgkmcnt(0) vmcnt(16)" ::: "memory");
        __builtin_amdgcn_sched_barrier(0);
        __builtin_amdgcn_s_barrier();
        __builtin_amdgcn_sched_barrier(0);
        #pragma unroll
        for (int j = 0; j < 4; ++j) {
            if (act[j]) {
                int s = ss[j], m = ms[j];
                float gi = G[m * 20 + s]         + Xs[buf][s][m];
                float gf = G[(m + 50) * 20 + s]  + Xs[buf][s][m + 50];
                float gg = G[(m + 100) * 20 + s] + Xs[buf][s][m + 100];
                float go = G[(m + 150) * 20 + s] + Xs[buf][s][m + 150];
                c_reg[j] = fsig2(gf) * c_reg[j] + fsig2(gi) * ftanh2(gg);
                float h = fsig2(go) * ftanh2(c_reg[j]);
                unsigned short hh, hl;
                split2(h, hh, hl);
                Ah[(m >> 3) * 128 + s * 8 + (m & 7)] = hh;
                Al[(m >> 3) * 128 + s * 8 + (m & 7)] = hl;
                x[((size_t)(b0 + s) * 64 + idx) * 100 + dir * 50 + m] = h;
            }
        }
        // barrier #2: Ah/Al visible; h-stores/prefetch stay in flight.
        asm volatile("s_waitcnt lgkmcnt(0)" ::: "memory");
        __builtin_amdgcn_sched_barrier(0);
        __builtin_amdgcn_s_barrier();
        __builtin_amdgcn_sched_barrier(0);
    }
}

// ---------------------------------------------------------------------------
// K4: ChildSum TreeLSTM + masked pool + classifier. One block = one sentence.
// ---------------------------------------------------------------------------
__global__ __launch_bounds__(256)
void tree_kernel(const float* __restrict__ C2,
                 const float* __restrict__ Uw, const float* __restrict__ Ub,
                 const float* __restrict__ Fw, const float* __restrict__ Fb,
                 const float* __restrict__ tmask,
                 const float* __restrict__ Cw, const float* __restrict__ Cb,
                 float* __restrict__ out) {
    const int b = blockIdx.x;
    const int tid = threadIdx.x;

    __shared__ __align__(16) float h_sum[32][52];
    __shared__ __align__(16) float fc_sum[32][52];
    __shared__ __align__(16) float hcur[32][52];
    __shared__ __align__(16) float mcur[32][52];
    __shared__ float msg[16][152];
    __shared__ float hfin[64][50];
    __shared__ float pool[52];

    const int rU = (tid < 150) ? tid : 0;
    const int rF = tid % 50;
    float ur[50], fr[50];
    #pragma unroll
    for (int k = 0; k < 50; ++k) ur[k] = Uw[rU * 50 + k];
    #pragma unroll
    for (int k = 0; k < 50; ++k) fr[k] = Fw[rF * 50 + k];
    const float ub = Ub[rU];
    const float fb = Fb[rF];

    for (int q = tid; q < 32 * 52; q += 256) {
        h_sum[q / 52][q % 52] = 0.0f;
        fc_sum[q / 52][q % 52] = 0.0f;
    }
    __syncthreads();

    const float* c2b = C2 + (size_t)b * 64 * 200;

    for (int lvl = 6; lvl >= 0; --lvl) {
        const int lo = (1 << lvl) - 1;
        const int hi = min((1 << (lvl + 1)) - 2, 63);
        const int A = hi - lo + 1;
        const int chn = max(0, min(hi, 31) - lo + 1);

        if (tid < 150) {
            for (int a = 0; a < chn; ++a) {
                float acc = ub;
                #pragma unroll
                for (int k4 = 0; k4 < 12; ++k4) {
                    float4 h4 = *(const float4*)&h_sum[lo + a][k4 * 4];
                    acc += ur[k4*4+0]*h4.x + ur[k4*4+1]*h4.y + ur[k4*4+2]*h4.z + ur[k4*4+3]*h4.w;
                }
                acc += ur[48]*h_sum[lo + a][48] + ur[49]*h_sum[lo + a][49];
                msg[a][tid] = acc;
            }
        }
        __syncthreads();

        for (int q = tid; q < A * 50; q += 256) {
            int a = q / 50, m = q - a * 50;
            int loc = lo + a;
            const float* base = c2b + (size_t)loc * 200;
            bool ch = (a < chn);
            float ig = base[m]       + (ch ? msg[a][m]       : 0.0f);
            float og = base[50 + m]  + (ch ? msg[a][50 + m]  : 0.0f);
            float ug = base[100 + m] + (ch ? msg[a][100 + m] : 0.0f);
            float cn = fsig(ig) * ftanh(ug) + (ch ? fc_sum[loc][m] : 0.0f);
            float hn = base[150 + m] + fsig(og) * ftanh(cn);
            hcur[a][m] = hn;
            mcur[a][m] = cn;
            hfin[loc][m] = hn;
        }
        __syncthreads();

        if (tid < 250) {
            for (int a = tid / 50; a < A; a += 5) {
                float acc = fb;
                #pragma unroll
                for (int k4 = 0; k4 < 12; ++k4) {
                    float4 h4 = *(const float4*)&hcur[a][k4 * 4];
                    acc += fr[k4*4+0]*h4.x + fr[k4*4+1]*h4.y + fr[k4*4+2]*h4.z + fr[k4*4+3]*h4.w;
                }
                acc += fr[48]*hcur[a][48] + fr[49]*hcur[a][49];
                mcur[a][rF] = fsig(acc) * mcur[a][rF];
            }
        }
        __syncthreads();

        if (lvl > 0) {
            const int plo = (lo - 1) >> 1, phi = (hi - 1) >> 1;
            const int P = phi - plo + 1;
            for (int q = tid; q < P * 50; q += 256) {
                int pi = q / 50, m = q - pi * 50;
                int p = plo + pi;
                int c1 = 2 * p + 1, c2i = 2 * p + 2;
                float hs = hcur[c1 - lo][m];
                float fs = mcur[c1 - lo][m];
                if (c2i <= hi) { hs += hcur[c2i - lo][m]; fs += mcur[c2i - lo][m]; }
                h_sum[p][m] += hs;
                fc_sum[p][m] += fs;
            }
        }
        __syncthreads();
    }

    const float* tm = tmask + (size_t)b * 64;
    if (tid < 50) {
        float acc = 0.0f, ws = 0.0f;
        for (int l = 0; l < 64; ++l) {
            float wv = tm[l];
            ws += wv;
            acc += wv * hfin[l][tid];
        }
        float p = acc / ws;
        pool[tid] = p;
        out[3072 + (size_t)b * 50 + tid] = p;
    }
    __syncthreads();
    if (tid < 3) {
        float acc = Cb[tid];
        #pragma unroll
        for (int m = 0; m < 50; ++m) acc += Cw[tid * 50 + m] * pool[m];
        out[(size_t)b * 3 + tid] = acc;
    }
}

// ---------------------------------------------------------------------------
extern "C" void kernel_launch(void* const* d_in, const int* in_sizes, int n_in,
                              void* d_out, int out_size, void* d_ws, size_t ws_size,
                              hipStream_t stream) {
    (void)in_sizes; (void)n_in; (void)out_size; (void)ws_size;
    const int*   ids   = (const int*)d_in[0];
    const float* tmask = (const float*)d_in[3];
    const float* table = (const float*)d_in[5];
    const float* Wihf  = (const float*)d_in[6];
    const float* Whhf  = (const float*)d_in[7];
    const float* bf    = (const float*)d_in[8];
    const float* Wihb  = (const float*)d_in[9];
    const float* Whhb  = (const float*)d_in[10];
    const float* bb    = (const float*)d_in[11];
    const float* Wiou  = (const float*)d_in[12];
    const float* Uiouw = (const float*)d_in[13];
    const float* Uioub = (const float*)d_in[14];
    const float* biou  = (const float*)d_in[15];
    const float* Ufw   = (const float*)d_in[16];
    const float* Ufb   = (const float*)d_in[17];
    const float* Hw    = (const float*)d_in[18];
    const float* Hb    = (const float*)d_in[19];
    const float* Cw    = (const float*)d_in[20];
    const float* Cb    = (const float*)d_in[21];
    float* out = (float*)d_out;

    float* wsf = (float*)d_ws;
    float* xg = wsf;                                  // 65536*400 f32 (C2 later)
    float* x  = wsf + (size_t)65536 * 400;            // 65536*100 f32
    float* C2 = wsf;
    unsigned short* B1c = (unsigned short*)(wsf + 32768000);  // 10*2*4*448*8 ush
    unsigned short* B3c = (unsigned short*)(wsf + 32911360);  // 4*2*4*256*8 ush
    unsigned short* Whc = (unsigned short*)(wsf + 32944128);  // 2 * WHC_DIR ush

    // K0: weight pre-conversion (hi|lo bf16, chunked layout)
    conv_kernel<<<70, 256, 0, stream>>>(Wihf, Wihb, 200, 300, 400, 448, 10, B1c);
    conv_kernel<<<16, 256, 0, stream>>>(Wiou, Hw, 150, 100, 200, 256, 4, B3c);
    conv_kernel<<<7, 256, 0, stream>>>(Whhf, Whhf, 200, 50, 200, 208, 2, Whc);
    conv_kernel<<<7, 256, 0, stream>>>(Whhb, Whhb, 200, 50, 200, 208, 2, Whc + WHC_DIR);
    // K1: xg = gather(embed)@[W_ih_f;W_ih_b]^T + bias   (N x 400)
    gemm_split<448, 10, 300, 400, true><<<1024, 256, 0, stream>>>(
        table, ids, B1c, bf, bb, 200, xg);
    // K2: MFMA BiLSTM -> x (N x 100) = [hf | hb]
    lstm_mfma<<<128, 256, 0, stream>>>(xg, Whc, x);
    // K3: C2 = x@[W_iou^T | H_w^T] + [b_iou | H_b]   (N x 200)
    gemm_split<256, 4, 100, 200, false><<<1024, 256, 0, stream>>>(
        x, nullptr, B3c, biou, Hb, 150, C2);
    // K4: TreeLSTM + pool + classifier
    tree_kernel<<<1024, 256, 0, stream>>>(
        C2, Uiouw, Uioub, Ufw, Ufb, tmask, Cw, Cb, out);
}

// Round 6
// 475.676 us; speedup vs baseline: 1.0400x; 1.0400x over previous
//
#include <hip/hip_runtime.h>

// Problem constants: B=1024, L=64, N=65536, V=100000, E=300, RH=M=50, NC=3
// tree: balanced binary, parent=(i-1)//2, depths 0..6, locs 0..31 have children

typedef __attribute__((ext_vector_type(8))) short bf16x8;
typedef __attribute__((ext_vector_type(4))) float f32x4;

// ---- activations ----
__device__ __forceinline__ float fsig(float x) { return 1.0f / (1.0f + __expf(-x)); }
__device__ __forceinline__ float ftanh(float x) {
    float a = fabsf(x);
    float t = __expf(2.0f * a);
    float r = 1.0f - 2.0f / (t + 1.0f);
    return copysignf(r, x);
}
__device__ __forceinline__ float fsig2(float x) {
    float e = __builtin_amdgcn_exp2f(-1.4426950408889634f * x);
    return __builtin_amdgcn_rcpf(1.0f + e);
}
__device__ __forceinline__ float ftanh2(float x) {
    float e = __builtin_amdgcn_exp2f(2.8853900817779268f * x);
    return 1.0f - 2.0f * __builtin_amdgcn_rcpf(1.0f + e);
}

// round-to-nearest-even f32 -> bf16 (returns upper 16 bits)
__device__ __forceinline__ unsigned short rne_bf16(float f) {
    unsigned u = __builtin_bit_cast(unsigned, f);
    unsigned r = u + 0x7fffu + ((u >> 16) & 1u);
    return (unsigned short)(r >> 16);
}
// fp32 -> bf16 hi + bf16 lo (RNE both limbs; combined residual ~2^-17 rel, unbiased)
__device__ __forceinline__ void split2(float f, unsigned short& h, unsigned short& l) {
    h = rne_bf16(f);
    float fh = __builtin_bit_cast(float, ((unsigned)h) << 16);
    float r = f - fh;   // exact (Sterbenz)
    l = rne_bf16(r);
}

__device__ __forceinline__ void async_lds16(const void* g, void* l) {
    __builtin_amdgcn_global_load_lds(
        (const __attribute__((address_space(1))) unsigned int*)g,
        (__attribute__((address_space(3))) unsigned int*)l, 16, 0, 0);
}

__device__ __forceinline__ bf16x8 pack8(const unsigned short* h) {
    bf16x8 v;
    #pragma unroll
    for (int e = 0; e < 8; ++e) v[e] = (short)h[e];
    return v;
}

// ---------------------------------------------------------------------------
// K0: convert weights [B1;B2] (rows = output cols, K contraction) to chunked
// hi|lo bf16 layout for one COLUMN BLOCK [n0, n0+BN):
//   out[(((c*2+h)*4 + kq)*BN + n)*8 + e] covers k = c*32 + kq*8 + e,
//   global col = n0 + n.  col >= Rreal or k >= K zero-filled.
// Linear per chunk (async-copy staging is a straight memcpy).
// Total size per call: KCH*2*4*BN*8 shorts.
// ---------------------------------------------------------------------------
__global__ void conv_kernel(const float* __restrict__ B1, const float* __restrict__ B2,
                            int split, int K, int Rreal, int BN, int KCH, int n0,
                            unsigned short* __restrict__ out) {
    int q = blockIdx.x * 256 + threadIdx.x;
    int total = KCH * 4 * BN;
    if (q >= total) return;
    int n  = q % BN;
    int kq = (q / BN) & 3;
    int c  = q / (BN * 4);
    int ng = n0 + n;
    const float* row = (ng < split) ? (B1 + (size_t)ng * K) : (B2 + (size_t)(ng - split) * K);
    unsigned short h[8], l[8];
    #pragma unroll
    for (int e = 0; e < 8; ++e) {
        int k = c * 32 + kq * 8 + e;
        float v = (ng < Rreal && k < K) ? row[k] : 0.0f;
        split2(v, h[e], l[e]);
    }
    size_t hb = ((((size_t)c * 2 + 0) * 4 + kq) * BN + n) * 8;
    size_t lb = ((((size_t)c * 2 + 1) * 4 + kq) * BN + n) * 8;
    *(ushort4*)&out[hb]     = make_ushort4(h[0], h[1], h[2], h[3]);
    *(ushort4*)&out[hb + 4] = make_ushort4(h[4], h[5], h[6], h[7]);
    *(ushort4*)&out[lb]     = make_ushort4(l[0], l[1], l[2], l[3]);
    *(ushort4*)&out[lb + 4] = make_ushort4(l[4], l[5], l[6], l[7]);
}

// ---------------------------------------------------------------------------
// Split-bf16 MFMA GEMM, round-6 "pipelined row-split" form.
// Round-3 post-mortem: the 97us was per-chunk __syncthreads draining the
// just-issued B-DMA (full HBM/L2 latency exposed 10x per block).  Round-5
// post-mortem: zero-LDS was VALU-bound (4x redundant split2) + global-B
// latency on the MFMA path.  This version:
//   - waves split ROWS (wave w owns rows w*16..+15): A-frag is wave-private,
//     gathered+split2'd in-register (same VALU cost as round-3 staging),
//     NO As LDS, NO As barrier;
//   - B double-buffered in LDS via global_load_lds, staged one chunk ahead;
//     block covers BN=NCOLS-half columns (2 col-blocks per row-tile) so
//     2*chunk fits 64KB (2 x 64*BN shorts);
//   - ONE barrier per chunk: s_waitcnt lgkmcnt(0) vmcnt(2); s_barrier.
//     vmcnt audit (order pinned by sched_barrier, uniform per wave): per
//     chunk each wave issues exactly DMA_PT DMA + 2 A-loads; at the barrier
//     of chunk c the ops newer than DMA(c) are just the 2 A-loads(c) ->
//     vmcnt(2) proves own DMA(c) landed; s_barrier makes it block-wide.
//     DMA(c) was issued one full chunk earlier -> latency hidden under
//     MFMA(c-1).  lgkmcnt(0) at the barrier also fences buf reuse (reads of
//     buf[c-1] complete before anyone DMAs into it at chunk c+1).
// Tail: KREAL % 8 == 4 (300, 100): clamped loads + static fixup (valid
// elements are q[0..3]); dummy tail issues keep counts uniform.
// ---------------------------------------------------------------------------
template<int BN, int KCH, int KREAL, int NCOLS, bool GATHER>
__global__ __launch_bounds__(256, 2)
void gemm_pipe(const float* __restrict__ A, const int* __restrict__ ids,
               const unsigned short* __restrict__ Bc0,
               const unsigned short* __restrict__ Bc1,
               const float* __restrict__ bias1, const float* __restrict__ bias2,
               int split, float* __restrict__ C) {
    static_assert(KREAL % 8 == 4, "tail fixup assumes KREAL%8==4");
    static_assert(KCH % 2 == 0, "paired steps");
    constexpr int NTW = BN / 16;            // 16-col tiles per wave (all cols)
    constexpr int CHB = 64 * BN;            // shorts per chunk (2h*4kq*BN*8)
    constexpr int DMA_PT = CHB / 2048;      // 16B DMA instrs per thread per chunk
    __shared__ __align__(16) unsigned short Bt[2][CHB];

    const int tid = threadIdx.x;
    const int cb = blockIdx.x & 1;
    const int m0 = (blockIdx.x >> 1) * 64;
    const int w = tid >> 6, lane = tid & 63;
    const int r16 = lane & 15, quad = lane >> 4;
    const int k0b = quad * 8;

    const unsigned short* Bc = cb ? Bc1 : Bc0;
    const int myrow = w * 16 + r16;
    const float* arow = GATHER ? (A + (size_t)ids[m0 + myrow] * KREAL)
                               : (A + (size_t)(m0 + myrow) * KREAL);

    auto stageB = [&](int c, int slot) {
        int cc = (c < KCH) ? c : (KCH - 1);   // tail dummy (harmless restage)
        const unsigned short* src = Bc + (size_t)cc * CHB + tid * 8;
        unsigned short* dst = &Bt[slot][tid * 8];
        #pragma unroll
        for (int i = 0; i < DMA_PT; ++i)
            async_lds16(src + i * 2048, dst + i * 2048);
    };
    auto issueA = [&](int c, float4& p, float4& q) {
        int k0 = c * 32 + k0b;                // may exceed KREAL-8 (tail/dummy)
        const float* src = arow + ((k0 <= KREAL - 8) ? k0 : (KREAL - 8));
        p = *(const float4*)src;
        q = *(const float4*)(src + 4);
    };

    f32x4 acc[NTW] = {};

    auto step = [&](int c, float4& cp, float4& cq, float4& np, float4& nq) {
        // barrier: own DMA(c) landed (vmcnt(2): only A-loads(c) may remain);
        // all waves' ds_reads of buf[(c-1)&1] done (lgkmcnt 0) -> safe reuse.
        asm volatile("s_waitcnt lgkmcnt(0) vmcnt(2)" ::: "memory");
        __builtin_amdgcn_sched_barrier(0);
        __builtin_amdgcn_s_barrier();
        __builtin_amdgcn_sched_barrier(0);
        stageB(c + 1, (c + 1) & 1);           // DMA_PT instrs
        __builtin_amdgcn_sched_barrier(0);    // pin VMEM order: DMA then A-loads
        issueA(c + 1, np, nq);                // 2 instrs
        __builtin_amdgcn_sched_barrier(0);
        // A frags for chunk c from (cp,cq)
        float ar[8];
        int k0 = c * 32 + k0b;
        if (k0 <= KREAL - 8) {
            ar[0]=cp.x; ar[1]=cp.y; ar[2]=cp.z; ar[3]=cp.w;
            ar[4]=cq.x; ar[5]=cq.y; ar[6]=cq.z; ar[7]=cq.w;
        } else {
            // clamped load base = KREAL-8; valid ks (if any) are q[0..3]
            float qq0 = cq.x, qq1 = cq.y, qq2 = cq.z, qq3 = cq.w;
            ar[0] = (k0 + 0 < KREAL) ? qq0 : 0.0f;
            ar[1] = (k0 + 1 < KREAL) ? qq1 : 0.0f;
            ar[2] = (k0 + 2 < KREAL) ? qq2 : 0.0f;
            ar[3] = (k0 + 3 < KREAL) ? qq3 : 0.0f;
            ar[4] = 0.0f; ar[5] = 0.0f; ar[6] = 0.0f; ar[7] = 0.0f;
        }
        unsigned short hh[8], ll[8];
        #pragma unroll
        for (int e = 0; e < 8; ++e) split2(ar[e], hh[e], ll[e]);
        bf16x8 ah = pack8(hh), al = pack8(ll);
        const unsigned short* bb = &Bt[c & 1][0];
        #pragma unroll
        for (int t = 0; t < NTW; ++t) {
            bf16x8 bh = *(const bf16x8*)&bb[((0 * 4 + quad) * BN + t * 16 + r16) * 8];
            bf16x8 bl = *(const bf16x8*)&bb[((1 * 4 + quad) * BN + t * 16 + r16) * 8];
            acc[t] = __builtin_amdgcn_mfma_f32_16x16x32_bf16(ah, bh, acc[t], 0, 0, 0);
            acc[t] = __builtin_amdgcn_mfma_f32_16x16x32_bf16(al, bh, acc[t], 0, 0, 0);
            acc[t] = __builtin_amdgcn_mfma_f32_16x16x32_bf16(ah, bl, acc[t], 0, 0, 0);
        }
    };

    float4 pA, qA, pB, qB;
    stageB(0, 0);
    __builtin_amdgcn_sched_barrier(0);
    issueA(0, pA, qA);
    __builtin_amdgcn_sched_barrier(0);

    #pragma unroll 1
    for (int c2 = 0; c2 < KCH / 2; ++c2) {
        step(2 * c2,     pA, qA, pB, qB);
        step(2 * c2 + 1, pB, qB, pA, qA);
    }

    #pragma unroll
    for (int t = 0; t < NTW; ++t) {
        int ncol = cb * BN + t * 16 + r16;
        if (ncol < NCOLS) {
            float bv = (ncol < split) ? bias1[ncol] : bias2[ncol - split];
            #pragma unroll
            for (int r = 0; r < 4; ++r) {
                int mrow = m0 + w * 16 + quad * 4 + r;
                C[(size_t)mrow * NCOLS + ncol] = acc[t][r] + bv;
            }
        }
    }
}

// ---------------------------------------------------------------------------
// K2: MFMA-batched BiLSTM. Block = (dir, 16 sentences), 256 thr = 4 waves.
// (round-3 verified counted-vmcnt version, unchanged)
// ---------------------------------------------------------------------------
constexpr int WHC_DIR = 2 * 2 * 4 * 208 * 8;   // shorts per direction = 26624

__global__ __launch_bounds__(256)
void lstm_mfma(const float* __restrict__ xg, const unsigned short* __restrict__ Whc,
               float* __restrict__ x) {
    const int bi = blockIdx.x;
    const int dir = bi & 1;
    const int b0 = (bi >> 1) * 16;
    const int tid = threadIdx.x;
    const int w = tid >> 6, lane = tid & 63;
    const int r16 = lane & 15, quad = lane >> 4;

    __shared__ __align__(16) unsigned short Ah[8 * 16 * 8];  // [kq][s][8]
    __shared__ __align__(16) unsigned short Al[8 * 16 * 8];
    __shared__ __align__(16) float G[208 * 20];              // [gate][sent pad20]
    __shared__ __align__(16) float Xs[3][16][268];           // xg ring (lead 2)

    const int n0 = (w == 0) ? 0 : (w == 1) ? 4 : (w == 2) ? 7 : 10;
    const int nc = (w == 0) ? 4 : 3;

    const unsigned short* Wd = Whc + (size_t)dir * WHC_DIR;
    bf16x8 bfr[4][2][2];   // [tile][chunk][hi/lo]
    #pragma unroll
    for (int t = 0; t < 4; ++t) {
        int col = (n0 + ((t < nc) ? t : 0)) * 16 + r16;
        #pragma unroll
        for (int c = 0; c < 2; ++c)
            #pragma unroll
            for (int h = 0; h < 2; ++h)
                bfr[t][c][h] = *(const bf16x8*)&Wd[((((size_t)c * 2 + h) * 4 + quad) * 208 + col) * 8];
    }

    for (int q = tid; q < 512; q += 256) {
        ((unsigned*)Ah)[q] = 0u;
        ((unsigned*)Al)[q] = 0u;
    }

    // gate-item mapping: q = w*200 + lane + 64*j  (uniform 4 store instrs/wave)
    int ss[4], ms[4];
    bool act[4];
    #pragma unroll
    for (int j = 0; j < 4; ++j) {
        int q = w * 200 + lane + 64 * j;
        ss[j] = q & 15;
        ms[j] = q >> 4;
        act[j] = (lane + 64 * j) < 200;
    }
    float c_reg[4] = {0.0f, 0.0f, 0.0f, 0.0f};

    // prologue: steps 0 and 1 into ring slots 0,1 (drained by __syncthreads)
    #pragma unroll
    for (int p = 0; p < 2; ++p) {
        int idx0 = dir ? (63 - p) : p;
        #pragma unroll
        for (int i = 0; i < 4; ++i) {
            int s = w * 4 + i;
            const float* src = xg + ((size_t)(b0 + s) * 64 + idx0) * 400 + dir * 200 + lane * 4;
            async_lds16(src, &Xs[p][s][lane * 4]);
        }
    }
    __syncthreads();

    for (int step = 0; step < 64; ++step) {
        const int buf = step % 3;
        const int idx = dir ? (63 - step) : step;
        {
            int stepn = step + 2; if (stepn > 63) stepn = 63;
            const int slot = (step + 2) % 3;
            const int idxn = dir ? (63 - stepn) : stepn;
            #pragma unroll
            for (int i = 0; i < 4; ++i) {
                int s = w * 4 + i;
                const float* src = xg + ((size_t)(b0 + s) * 64 + idxn) * 400 + dir * 200 + lane * 4;
                async_lds16(src, &Xs[slot][s][lane * 4]);
            }
            __builtin_amdgcn_sched_barrier(0);
        }
        bf16x8 ah[2], al[2];
        #pragma unroll
        for (int c = 0; c < 2; ++c) {
            ah[c] = *(const bf16x8*)&Ah[((c * 4 + quad) * 16 + r16) * 8];
            al[c] = *(const bf16x8*)&Al[((c * 4 + quad) * 16 + r16) * 8];
        }
        f32x4 acc[4] = {};
        #pragma unroll
        for (int t = 0; t < 4; ++t) {
            if (t < nc) {
                #pragma unroll
                for (int c = 0; c < 2; ++c) {
                    acc[t] = __builtin_amdgcn_mfma_f32_16x16x32_bf16(ah[c], bfr[t][c][0], acc[t], 0, 0, 0);
                    acc[t] = __builtin_amdgcn_mfma_f32_16x16x32_bf16(al[c], bfr[t][c][0], acc[t], 0, 0, 0);
                    acc[t] = __builtin_amdgcn_mfma_f32_16x16x32_bf16(ah[c], bfr[t][c][1], acc[t], 0, 0, 0);
                }
            }
        }
        #pragma unroll
        for (int t = 0; t < 4; ++t) {
            if (t < nc) {
                int col = (n0 + t) * 16 + r16;
                *(f32x4*)&G[col * 20 + quad * 4] = acc[t];
            }
        }
        asm volatile("s_waitcnt lgkmcnt(0) vmcnt(16)" ::: "memory");
        __builtin_amdgcn_sched_barrier(0);
        __builtin_amdgcn_s_barrier();
        __builtin_amdgcn_sched_barrier(0);
        #pragma unroll
        for (int j = 0; j < 4; ++j) {
            if (act[j]) {
                int s = ss[j], m = ms[j];
                float gi = G[m * 20 + s]         + Xs[buf][s][m];
                float gf = G[(m + 50) * 20 + s]  + Xs[buf][s][m + 50];
                float gg = G[(m + 100) * 20 + s] + Xs[buf][s][m + 100];
                float go = G[(m + 150) * 20 + s] + Xs[buf][s][m + 150];
                c_reg[j] = fsig2(gf) * c_reg[j] + fsig2(gi) * ftanh2(gg);
                float h = fsig2(go) * ftanh2(c_reg[j]);
                unsigned short hh, hl;
                split2(h, hh, hl);
                Ah[(m >> 3) * 128 + s * 8 + (m & 7)] = hh;
                Al[(m >> 3) * 128 + s * 8 + (m & 7)] = hl;
                x[((size_t)(b0 + s) * 64 + idx) * 100 + dir * 50 + m] = h;
            }
        }
        asm volatile("s_waitcnt lgkmcnt(0)" ::: "memory");
        __builtin_amdgcn_sched_barrier(0);
        __builtin_amdgcn_s_barrier();
        __builtin_amdgcn_sched_barrier(0);
    }
}

// ---------------------------------------------------------------------------
// K4: ChildSum TreeLSTM + masked pool + classifier. One block = one sentence.
// ---------------------------------------------------------------------------
__global__ __launch_bounds__(256)
void tree_kernel(const float* __restrict__ C2,
                 const float* __restrict__ Uw, const float* __restrict__ Ub,
                 const float* __restrict__ Fw, const float* __restrict__ Fb,
                 const float* __restrict__ tmask,
                 const float* __restrict__ Cw, const float* __restrict__ Cb,
                 float* __restrict__ out) {
    const int b = blockIdx.x;
    const int tid = threadIdx.x;

    __shared__ __align__(16) float h_sum[32][52];
    __shared__ __align__(16) float fc_sum[32][52];
    __shared__ __align__(16) float hcur[32][52];
    __shared__ __align__(16) float mcur[32][52];
    __shared__ float msg[16][152];
    __shared__ float hfin[64][50];
    __shared__ float pool[52];

    const int rU = (tid < 150) ? tid : 0;
    const int rF = tid % 50;
    float ur[50], fr[50];
    #pragma unroll
    for (int k = 0; k < 50; ++k) ur[k] = Uw[rU * 50 + k];
    #pragma unroll
    for (int k = 0; k < 50; ++k) fr[k] = Fw[rF * 50 + k];
    const float ub = Ub[rU];
    const float fb = Fb[rF];

    for (int q = tid; q < 32 * 52; q += 256) {
        h_sum[q / 52][q % 52] = 0.0f;
        fc_sum[q / 52][q % 52] = 0.0f;
    }
    __syncthreads();

    const float* c2b = C2 + (size_t)b * 64 * 200;

    for (int lvl = 6; lvl >= 0; --lvl) {
        const int lo = (1 << lvl) - 1;
        const int hi = min((1 << (lvl + 1)) - 2, 63);
        const int A = hi - lo + 1;
        const int chn = max(0, min(hi, 31) - lo + 1);

        if (tid < 150) {
            for (int a = 0; a < chn; ++a) {
                float acc = ub;
                #pragma unroll
                for (int k4 = 0; k4 < 12; ++k4) {
                    float4 h4 = *(const float4*)&h_sum[lo + a][k4 * 4];
                    acc += ur[k4*4+0]*h4.x + ur[k4*4+1]*h4.y + ur[k4*4+2]*h4.z + ur[k4*4+3]*h4.w;
                }
                acc += ur[48]*h_sum[lo + a][48] + ur[49]*h_sum[lo + a][49];
                msg[a][tid] = acc;
            }
        }
        __syncthreads();

        for (int q = tid; q < A * 50; q += 256) {
            int a = q / 50, m = q - a * 50;
            int loc = lo + a;
            const float* base = c2b + (size_t)loc * 200;
            bool ch = (a < chn);
            float ig = base[m]       + (ch ? msg[a][m]       : 0.0f);
            float og = base[50 + m]  + (ch ? msg[a][50 + m]  : 0.0f);
            float ug = base[100 + m] + (ch ? msg[a][100 + m] : 0.0f);
            float cn = fsig(ig) * ftanh(ug) + (ch ? fc_sum[loc][m] : 0.0f);
            float hn = base[150 + m] + fsig(og) * ftanh(cn);
            hcur[a][m] = hn;
            mcur[a][m] = cn;
            hfin[loc][m] = hn;
        }
        __syncthreads();

        if (tid < 250) {
            for (int a = tid / 50; a < A; a += 5) {
                float acc = fb;
                #pragma unroll
                for (int k4 = 0; k4 < 12; ++k4) {
                    float4 h4 = *(const float4*)&hcur[a][k4 * 4];
                    acc += fr[k4*4+0]*h4.x + fr[k4*4+1]*h4.y + fr[k4*4+2]*h4.z + fr[k4*4+3]*h4.w;
                }
                acc += fr[48]*hcur[a][48] + fr[49]*hcur[a][49];
                mcur[a][rF] = fsig(acc) * mcur[a][rF];
            }
        }
        __syncthreads();

        if (lvl > 0) {
            const int plo = (lo - 1) >> 1, phi = (hi - 1) >> 1;
            const int P = phi - plo + 1;
            for (int q = tid; q < P * 50; q += 256) {
                int pi = q / 50, m = q - pi * 50;
                int p = plo + pi;
                int c1 = 2 * p + 1, c2i = 2 * p + 2;
                float hs = hcur[c1 - lo][m];
                float fs = mcur[c1 - lo][m];
                if (c2i <= hi) { hs += hcur[c2i - lo][m]; fs += mcur[c2i - lo][m]; }
                h_sum[p][m] += hs;
                fc_sum[p][m] += fs;
            }
        }
        __syncthreads();
    }

    const float* tm = tmask + (size_t)b * 64;
    if (tid < 50) {
        float acc = 0.0f, ws = 0.0f;
        for (int l = 0; l < 64; ++l) {
            float wv = tm[l];
            ws += wv;
            acc += wv * hfin[l][tid];
        }
        float p = acc / ws;
        pool[tid] = p;
        out[3072 + (size_t)b * 50 + tid] = p;
    }
    __syncthreads();
    if (tid < 3) {
        float acc = Cb[tid];
        #pragma unroll
        for (int m = 0; m < 50; ++m) acc += Cw[tid * 50 + m] * pool[m];
        out[(size_t)b * 3 + tid] = acc;
    }
}

// ---------------------------------------------------------------------------
extern "C" void kernel_launch(void* const* d_in, const int* in_sizes, int n_in,
                              void* d_out, int out_size, void* d_ws, size_t ws_size,
                              hipStream_t stream) {
    (void)in_sizes; (void)n_in; (void)out_size; (void)ws_size;
    const int*   ids   = (const int*)d_in[0];
    const float* tmask = (const float*)d_in[3];
    const float* table = (const float*)d_in[5];
    const float* Wihf  = (const float*)d_in[6];
    const float* Whhf  = (const float*)d_in[7];
    const float* bf    = (const float*)d_in[8];
    const float* Wihb  = (const float*)d_in[9];
    const float* Whhb  = (const float*)d_in[10];
    const float* bb    = (const float*)d_in[11];
    const float* Wiou  = (const float*)d_in[12];
    const float* Uiouw = (const float*)d_in[13];
    const float* Uioub = (const float*)d_in[14];
    const float* biou  = (const float*)d_in[15];
    const float* Ufw   = (const float*)d_in[16];
    const float* Ufb   = (const float*)d_in[17];
    const float* Hw    = (const float*)d_in[18];
    const float* Hb    = (const float*)d_in[19];
    const float* Cw    = (const float*)d_in[20];
    const float* Cb    = (const float*)d_in[21];
    float* out = (float*)d_out;

    float* wsf = (float*)d_ws;
    float* xg = wsf;                                  // 65536*400 f32 (C2 later)
    float* x  = wsf + (size_t)65536 * 400;            // 65536*100 f32
    float* C2 = wsf;
    // col-block pre-converted weights (shorts), packed after x:
    unsigned short* B1cA = (unsigned short*)(wsf + 32768000);  // 10*2*4*224*8 = 143360 ush
    unsigned short* B1cB = (unsigned short*)(wsf + 32839680);  // 143360 ush
    unsigned short* B3cA = (unsigned short*)(wsf + 32911360);  //  4*2*4*128*8 =  32768 ush
    unsigned short* B3cB = (unsigned short*)(wsf + 32927744);  //  32768 ush
    unsigned short* Whc  = (unsigned short*)(wsf + 32944128);  //  2 * WHC_DIR ush

    // K0: weight pre-conversion (hi|lo bf16, chunked, per col-block)
    conv_kernel<<<35, 256, 0, stream>>>(Wihf, Wihb, 200, 300, 400, 224, 10,   0, B1cA);
    conv_kernel<<<35, 256, 0, stream>>>(Wihf, Wihb, 200, 300, 400, 224, 10, 224, B1cB);
    conv_kernel<<< 8, 256, 0, stream>>>(Wiou, Hw,   150, 100, 200, 128,  4,   0, B3cA);
    conv_kernel<<< 8, 256, 0, stream>>>(Wiou, Hw,   150, 100, 200, 128,  4, 128, B3cB);
    conv_kernel<<< 7, 256, 0, stream>>>(Whhf, Whhf, 200,  50, 200, 208,  2,   0, Whc);
    conv_kernel<<< 7, 256, 0, stream>>>(Whhb, Whhb, 200,  50, 200, 208,  2,   0, Whc + WHC_DIR);
    // K1: xg = gather(embed)@[W_ih_f;W_ih_b]^T + bias   (N x 400)
    gemm_pipe<224, 10, 300, 400, true><<<2048, 256, 0, stream>>>(
        table, ids, B1cA, B1cB, bf, bb, 200, xg);
    // K2: MFMA BiLSTM -> x (N x 100) = [hf | hb]
    lstm_mfma<<<128, 256, 0, stream>>>(xg, Whc, x);
    // K3: C2 = x@[W_iou^T | H_w^T] + [b_iou | H_b]   (N x 200)
    gemm_pipe<128, 4, 100, 200, false><<<2048, 256, 0, stream>>>(
        x, nullptr, B3cA, B3cB, biou, Hb, 150, C2);
    // K4: TreeLSTM + pool + classifier
    tree_kernel<<<1024, 256, 0, stream>>>(
        C2, Uiouw, Uioub, Ufw, Ufb, tmask, Cw, Cb, out);
}

// Round 7
// 423.569 us; speedup vs baseline: 1.1680x; 1.1230x over previous
//
#include <hip/hip_runtime.h>

// Problem constants: B=1024, L=64, N=65536, V=100000, E=300, RH=M=50, NC=3
// tree: balanced binary, parent=(i-1)//2, depths 0..6, locs 0..31 have children

typedef __attribute__((ext_vector_type(8))) short bf16x8;
typedef __attribute__((ext_vector_type(4))) float f32x4;

// ---- activations ----
__device__ __forceinline__ float fsig(float x) { return 1.0f / (1.0f + __expf(-x)); }
__device__ __forceinline__ float ftanh(float x) {
    float a = fabsf(x);
    float t = __expf(2.0f * a);
    float r = 1.0f - 2.0f / (t + 1.0f);
    return copysignf(r, x);
}
__device__ __forceinline__ float fsig2(float x) {
    float e = __builtin_amdgcn_exp2f(-1.4426950408889634f * x);
    return __builtin_amdgcn_rcpf(1.0f + e);
}
__device__ __forceinline__ float ftanh2(float x) {
    float e = __builtin_amdgcn_exp2f(2.8853900817779268f * x);
    return 1.0f - 2.0f * __builtin_amdgcn_rcpf(1.0f + e);
}

// round-to-nearest-even f32 -> bf16 (returns upper 16 bits)
__device__ __forceinline__ unsigned short rne_bf16(float f) {
    unsigned u = __builtin_bit_cast(unsigned, f);
    unsigned r = u + 0x7fffu + ((u >> 16) & 1u);
    return (unsigned short)(r >> 16);
}
// fp32 -> bf16 hi + bf16 lo (RNE both limbs; combined residual ~2^-17 rel, unbiased)
__device__ __forceinline__ void split2(float f, unsigned short& h, unsigned short& l) {
    h = rne_bf16(f);
    float fh = __builtin_bit_cast(float, ((unsigned)h) << 16);
    float r = f - fh;   // exact (Sterbenz)
    l = rne_bf16(r);
}

__device__ __forceinline__ void async_lds16(const void* g, void* l) {
    __builtin_amdgcn_global_load_lds(
        (const __attribute__((address_space(1))) unsigned int*)g,
        (__attribute__((address_space(3))) unsigned int*)l, 16, 0, 0);
}

__device__ __forceinline__ bf16x8 pack8(const unsigned short* h) {
    bf16x8 v;
    #pragma unroll
    for (int e = 0; e < 8; ++e) v[e] = (short)h[e];
    return v;
}

// ---------------------------------------------------------------------------
// K0 (fused): convert weights [B1;B2] (rows = output cols, K contraction) to
// chunked hi|lo bf16 layout: out[(((c*2+h)*4 + kq)*BN + n)*8 + e] covers
// k = c*32 + kq*8 + e.  n >= Rreal or k >= K zero-filled.  All 4 round-3
// conversions fused into ONE launch (sectioned by global item index) to cut
// dispatch count.
// ---------------------------------------------------------------------------
__device__ __forceinline__ void conv_item(int q, const float* __restrict__ B1,
                                          const float* __restrict__ B2,
                                          int split, int K, int Rreal, int BN,
                                          unsigned short* __restrict__ out) {
    int n  = q % BN;
    int kq = (q / BN) & 3;
    int c  = q / (BN * 4);
    const float* row = (n < split) ? (B1 + (size_t)n * K) : (B2 + (size_t)(n - split) * K);
    unsigned short h[8], l[8];
    #pragma unroll
    for (int e = 0; e < 8; ++e) {
        int k = c * 32 + kq * 8 + e;
        float v = (n < Rreal && k < K) ? row[k] : 0.0f;
        split2(v, h[e], l[e]);
    }
    size_t hb = ((((size_t)c * 2 + 0) * 4 + kq) * BN + n) * 8;
    size_t lb = ((((size_t)c * 2 + 1) * 4 + kq) * BN + n) * 8;
    *(ushort4*)&out[hb]     = make_ushort4(h[0], h[1], h[2], h[3]);
    *(ushort4*)&out[hb + 4] = make_ushort4(h[4], h[5], h[6], h[7]);
    *(ushort4*)&out[lb]     = make_ushort4(l[0], l[1], l[2], l[3]);
    *(ushort4*)&out[lb + 4] = make_ushort4(l[4], l[5], l[6], l[7]);
}

constexpr int WHC_DIR = 2 * 2 * 4 * 208 * 8;   // shorts per direction = 26624

__global__ void conv_fused(const float* __restrict__ Wihf, const float* __restrict__ Wihb,
                           const float* __restrict__ Wiou, const float* __restrict__ Hw,
                           const float* __restrict__ Whhf, const float* __restrict__ Whhb,
                           unsigned short* __restrict__ B1c,
                           unsigned short* __restrict__ B3c,
                           unsigned short* __restrict__ Whc) {
    int q = blockIdx.x * 256 + threadIdx.x;
    // section totals: KCH*4*BN
    // s1: (448,10) -> 17920 ; s2: (256,4) -> 4096 ; s3/s4: (208,2) -> 1664 each
    if (q < 17920) {
        conv_item(q, Wihf, Wihb, 200, 300, 400, 448, B1c);
    } else if (q < 22016) {
        conv_item(q - 17920, Wiou, Hw, 150, 100, 200, 256, B3c);
    } else if (q < 23680) {
        conv_item(q - 22016, Whhf, Whhf, 200, 50, 200, 208, Whc);
    } else if (q < 25344) {
        conv_item(q - 23680, Whhb, Whhb, 200, 50, 200, 208, Whc + WHC_DIR);
    }
}

// ---------------------------------------------------------------------------
// Split-bf16 MFMA GEMM (round-3 verified version, 97us @ K1). BM=64 rows,
// BN padded cols, 256 thr = 4 waves column-split. Conflict-free LDS:
// A [h][kq][64][8], B [h][kq][BN][8] (pre-converted, async-staged).
// 3 mfma terms: Ah*Bh + Al*Bh + Ah*Bl.
// ---------------------------------------------------------------------------
template<int BN, int KCH, int KREAL, int NCOLS, bool GATHER>
__global__ __launch_bounds__(256)
void gemm_split(const float* __restrict__ A, const int* __restrict__ ids,
                const unsigned short* __restrict__ Bc,
                const float* __restrict__ bias1, const float* __restrict__ bias2,
                int split, float* __restrict__ C) {
    constexpr int NTW = BN / 64;   // 16-col tiles per wave
    __shared__ __align__(16) unsigned short As[2 * 4 * 64 * 8];  // 8 KB
    __shared__ __align__(16) unsigned short Bt[64 * BN];

    const int tid = threadIdx.x;
    const int m0 = blockIdx.x * 64;
    const int w = tid >> 6, lane = tid & 63;
    const int r16 = lane & 15, quad = lane >> 4;
    const int wn = w * (BN / 4);

    const int mA = tid & 63, kqA = tid >> 6;
    const float* arow = GATHER ? (A + (size_t)ids[m0 + mA] * KREAL)
                               : (A + (size_t)(m0 + mA) * KREAL);

    float ar[8];
    {
        int k0 = kqA * 8;
        if (k0 + 8 <= KREAL) {
            float4 p = *(const float4*)(arow + k0);
            float4 q = *(const float4*)(arow + k0 + 4);
            ar[0]=p.x; ar[1]=p.y; ar[2]=p.z; ar[3]=p.w;
            ar[4]=q.x; ar[5]=q.y; ar[6]=q.z; ar[7]=q.w;
        } else {
            #pragma unroll
            for (int e = 0; e < 8; ++e) ar[e] = (k0 + e < KREAL) ? arow[k0 + e] : 0.0f;
        }
    }

    f32x4 acc[4][NTW] = {};

    for (int c = 0; c < KCH; ++c) {
        __syncthreads();
        {
            const unsigned short* src = Bc + (size_t)c * 64 * BN + tid * 8;
            #pragma unroll
            for (int i = 0; i < BN / 32; ++i)
                async_lds16(src + (size_t)i * 2048, Bt + i * 2048 + tid * 8);
        }
        {
            unsigned short h[8], l[8];
            #pragma unroll
            for (int e = 0; e < 8; ++e) split2(ar[e], h[e], l[e]);
            *(bf16x8*)&As[((0 * 4 + kqA) * 64 + mA) * 8] = pack8(h);
            *(bf16x8*)&As[((1 * 4 + kqA) * 64 + mA) * 8] = pack8(l);
        }
        __syncthreads();
        if (c + 1 < KCH) {
            int k0 = (c + 1) * 32 + kqA * 8;
            if (k0 + 8 <= KREAL) {
                float4 p = *(const float4*)(arow + k0);
                float4 q = *(const float4*)(arow + k0 + 4);
                ar[0]=p.x; ar[1]=p.y; ar[2]=p.z; ar[3]=p.w;
                ar[4]=q.x; ar[5]=q.y; ar[6]=q.z; ar[7]=q.w;
            } else {
                #pragma unroll
                for (int e = 0; e < 8; ++e) ar[e] = (k0 + e < KREAL) ? arow[k0 + e] : 0.0f;
            }
        }
        bf16x8 af[2][4];
        #pragma unroll
        for (int i = 0; i < 4; ++i) {
            af[0][i] = *(const bf16x8*)&As[((0 * 4 + quad) * 64 + i * 16 + r16) * 8];
            af[1][i] = *(const bf16x8*)&As[((1 * 4 + quad) * 64 + i * 16 + r16) * 8];
        }
        #pragma unroll
        for (int t = 0; t < NTW; ++t) {
            bf16x8 bh = *(const bf16x8*)&Bt[((0 * 4 + quad) * BN + wn + t * 16 + r16) * 8];
            bf16x8 bl = *(const bf16x8*)&Bt[((1 * 4 + quad) * BN + wn + t * 16 + r16) * 8];
            #pragma unroll
            for (int i = 0; i < 4; ++i) {
                acc[i][t] = __builtin_amdgcn_mfma_f32_16x16x32_bf16(af[0][i], bh, acc[i][t], 0, 0, 0);
                acc[i][t] = __builtin_amdgcn_mfma_f32_16x16x32_bf16(af[1][i], bh, acc[i][t], 0, 0, 0);
                acc[i][t] = __builtin_amdgcn_mfma_f32_16x16x32_bf16(af[0][i], bl, acc[i][t], 0, 0, 0);
            }
        }
    }

    #pragma unroll
    for (int t = 0; t < NTW; ++t) {
        int ncol = wn + t * 16 + r16;
        if (ncol < NCOLS) {
            float bv = (ncol < split) ? bias1[ncol] : bias2[ncol - split];
            #pragma unroll
            for (int i = 0; i < 4; ++i)
                #pragma unroll
                for (int r = 0; r < 4; ++r) {
                    int mrow = m0 + i * 16 + quad * 4 + r;
                    C[(size_t)mrow * NCOLS + ncol] = acc[i][t][r] + bv;
                }
        }
    }
}

// ---------------------------------------------------------------------------
// K2: MFMA-batched BiLSTM, round-7: 8 sentences/block -> 256 blocks (full
// GPU), halving the per-step gate-phase VALU, store instrs and DMA issue
// relative to the verified round-3 16-sentence version.  MFMA stays M=16
// with rows 8..15 permanently zero in Ah/Al (init-once).
//
// Counted-vmcnt sync (verified template, counts re-audited for 8 sents):
// per step each wave issues exactly 2 DMA loads + 2 h-store instrs, in
// pinned order.  At barrier #1 of step t (need L_t = P_t issued 2 steps
// earlier): newer ops = S_{t-2}(2) + P_{t+1}... precisely:
//   S_{t-2}(2) + P_{t+1}(2) + S_{t-1}(2) + P_{t+2}(2) = 8
// -> s_waitcnt vmcnt(8) waits for exactly L_t; uniform for every wave
// (q = w*100 + lane + 64*j: j=0 full wave, j=1 lanes<36 -> 2 store instrs
// per wave regardless of w).  Stores never waited on; prefetches stay in
// flight across both barriers.  Prologue __syncthreads drains L_0,L_1.
// ---------------------------------------------------------------------------
__global__ __launch_bounds__(256)
void lstm_mfma(const float* __restrict__ xg, const unsigned short* __restrict__ Whc,
               float* __restrict__ x) {
    const int bi = blockIdx.x;
    const int dir = bi & 1;
    const int b0 = (bi >> 1) * 8;
    const int tid = threadIdx.x;
    const int w = tid >> 6, lane = tid & 63;
    const int r16 = lane & 15, quad = lane >> 4;

    __shared__ __align__(16) unsigned short Ah[8 * 16 * 8];  // [kq][row16][8]
    __shared__ __align__(16) unsigned short Al[8 * 16 * 8];
    __shared__ __align__(16) float G[208 * 20];              // [gate][row pad20]
    __shared__ __align__(16) float Xs[3][8][268];            // xg ring (lead 2)

    const int n0 = (w == 0) ? 0 : (w == 1) ? 4 : (w == 2) ? 7 : 10;
    const int nc = (w == 0) ? 4 : 3;

    const unsigned short* Wd = Whc + (size_t)dir * WHC_DIR;
    bf16x8 bfr[4][2][2];   // [tile][chunk][hi/lo]
    #pragma unroll
    for (int t = 0; t < 4; ++t) {
        int col = (n0 + ((t < nc) ? t : 0)) * 16 + r16;
        #pragma unroll
        for (int c = 0; c < 2; ++c)
            #pragma unroll
            for (int h = 0; h < 2; ++h)
                bfr[t][c][h] = *(const bf16x8*)&Wd[((((size_t)c * 2 + h) * 4 + quad) * 208 + col) * 8];
    }

    for (int q = tid; q < 512; q += 256) {
        ((unsigned*)Ah)[q] = 0u;   // rows 8..15 stay zero forever
        ((unsigned*)Al)[q] = 0u;
    }

    // gate-item mapping: q = w*100 + lane + 64*j (j<2) -> s = q&7, m = q>>3.
    // Uniform per wave: j=0 all 64 lanes, j=1 lanes<36 -> 2 store instrs.
    int ss[2], ms[2];
    bool act[2];
    #pragma unroll
    for (int j = 0; j < 2; ++j) {
        int q = w * 100 + lane + 64 * j;
        ss[j] = q & 7;
        ms[j] = q >> 3;
        act[j] = (lane + 64 * j) < 100;
    }
    float c_reg[2] = {0.0f, 0.0f};

    // prologue: steps 0 and 1 into ring slots 0,1 (drained by __syncthreads)
    #pragma unroll
    for (int p = 0; p < 2; ++p) {
        int idx0 = dir ? (63 - p) : p;
        #pragma unroll
        for (int i = 0; i < 2; ++i) {
            int s = w * 2 + i;
            const float* src = xg + ((size_t)(b0 + s) * 64 + idx0) * 400 + dir * 200 + lane * 4;
            async_lds16(src, &Xs[p][s][lane * 4]);
        }
    }
    __syncthreads();

    for (int step = 0; step < 64; ++step) {
        const int buf = step % 3;
        const int idx = dir ? (63 - step) : step;
        {
            int stepn = step + 2; if (stepn > 63) stepn = 63;
            const int slot = (step + 2) % 3;
            const int idxn = dir ? (63 - stepn) : stepn;
            #pragma unroll
            for (int i = 0; i < 2; ++i) {
                int s = w * 2 + i;
                const float* src = xg + ((size_t)(b0 + s) * 64 + idxn) * 400 + dir * 200 + lane * 4;
                async_lds16(src, &Xs[slot][s][lane * 4]);
            }
            __builtin_amdgcn_sched_barrier(0);   // pin issue before the counted wait
        }
        bf16x8 ah[2], al[2];
        #pragma unroll
        for (int c = 0; c < 2; ++c) {
            ah[c] = *(const bf16x8*)&Ah[((c * 4 + quad) * 16 + r16) * 8];
            al[c] = *(const bf16x8*)&Al[((c * 4 + quad) * 16 + r16) * 8];
        }
        f32x4 acc[4] = {};
        #pragma unroll
        for (int t = 0; t < 4; ++t) {
            if (t < nc) {
                #pragma unroll
                for (int c = 0; c < 2; ++c) {
                    acc[t] = __builtin_amdgcn_mfma_f32_16x16x32_bf16(ah[c], bfr[t][c][0], acc[t], 0, 0, 0);
                    acc[t] = __builtin_amdgcn_mfma_f32_16x16x32_bf16(al[c], bfr[t][c][0], acc[t], 0, 0, 0);
                    acc[t] = __builtin_amdgcn_mfma_f32_16x16x32_bf16(ah[c], bfr[t][c][1], acc[t], 0, 0, 0);
                }
            }
        }
        #pragma unroll
        for (int t = 0; t < 4; ++t) {
            if (t < nc) {
                int col = (n0 + t) * 16 + r16;
                *(f32x4*)&G[col * 20 + quad * 4] = acc[t];   // rows >=8 are zeros, ignored
            }
        }
        // barrier #1: G visible; own L_t landed via counted vmcnt(8).
        asm volatile("s_waitcnt lgkmcnt(0) vmcnt(8)" ::: "memory");
        __builtin_amdgcn_sched_barrier(0);
        __builtin_amdgcn_s_barrier();
        __builtin_amdgcn_sched_barrier(0);
        #pragma unroll
        for (int j = 0; j < 2; ++j) {
            if (act[j]) {
                int s = ss[j], m = ms[j];
                float gi = G[m * 20 + s]         + Xs[buf][s][m];
                float gf = G[(m + 50) * 20 + s]  + Xs[buf][s][m + 50];
                float gg = G[(m + 100) * 20 + s] + Xs[buf][s][m + 100];
                float go = G[(m + 150) * 20 + s] + Xs[buf][s][m + 150];
                c_reg[j] = fsig2(gf) * c_reg[j] + fsig2(gi) * ftanh2(gg);
                float h = fsig2(go) * ftanh2(c_reg[j]);
                unsigned short hh, hl;
                split2(h, hh, hl);
                Ah[(m >> 3) * 128 + s * 8 + (m & 7)] = hh;
                Al[(m >> 3) * 128 + s * 8 + (m & 7)] = hl;
                x[((size_t)(b0 + s) * 64 + idx) * 100 + dir * 50 + m] = h;
            }
        }
        // barrier #2: Ah/Al visible; h-stores/prefetch stay in flight.
        asm volatile("s_waitcnt lgkmcnt(0)" ::: "memory");
        __builtin_amdgcn_sched_barrier(0);
        __builtin_amdgcn_s_barrier();
        __builtin_amdgcn_sched_barrier(0);
    }
}

// ---------------------------------------------------------------------------
// K4: ChildSum TreeLSTM + masked pool + classifier. One block = one sentence.
// ---------------------------------------------------------------------------
__global__ __launch_bounds__(256)
void tree_kernel(const float* __restrict__ C2,
                 const float* __restrict__ Uw, const float* __restrict__ Ub,
                 const float* __restrict__ Fw, const float* __restrict__ Fb,
                 const float* __restrict__ tmask,
                 const float* __restrict__ Cw, const float* __restrict__ Cb,
                 float* __restrict__ out) {
    const int b = blockIdx.x;
    const int tid = threadIdx.x;

    __shared__ __align__(16) float h_sum[32][52];
    __shared__ __align__(16) float fc_sum[32][52];
    __shared__ __align__(16) float hcur[32][52];
    __shared__ __align__(16) float mcur[32][52];
    __shared__ float msg[16][152];
    __shared__ float hfin[64][50];
    __shared__ float pool[52];

    const int rU = (tid < 150) ? tid : 0;
    const int rF = tid % 50;
    float ur[50], fr[50];
    #pragma unroll
    for (int k = 0; k < 50; ++k) ur[k] = Uw[rU * 50 + k];
    #pragma unroll
    for (int k = 0; k < 50; ++k) fr[k] = Fw[rF * 50 + k];
    const float ub = Ub[rU];
    const float fb = Fb[rF];

    for (int q = tid; q < 32 * 52; q += 256) {
        h_sum[q / 52][q % 52] = 0.0f;
        fc_sum[q / 52][q % 52] = 0.0f;
    }
    __syncthreads();

    const float* c2b = C2 + (size_t)b * 64 * 200;

    for (int lvl = 6; lvl >= 0; --lvl) {
        const int lo = (1 << lvl) - 1;
        const int hi = min((1 << (lvl + 1)) - 2, 63);
        const int A = hi - lo + 1;
        const int chn = max(0, min(hi, 31) - lo + 1);

        if (tid < 150) {
            for (int a = 0; a < chn; ++a) {
                float acc = ub;
                #pragma unroll
                for (int k4 = 0; k4 < 12; ++k4) {
                    float4 h4 = *(const float4*)&h_sum[lo + a][k4 * 4];
                    acc += ur[k4*4+0]*h4.x + ur[k4*4+1]*h4.y + ur[k4*4+2]*h4.z + ur[k4*4+3]*h4.w;
                }
                acc += ur[48]*h_sum[lo + a][48] + ur[49]*h_sum[lo + a][49];
                msg[a][tid] = acc;
            }
        }
        __syncthreads();

        for (int q = tid; q < A * 50; q += 256) {
            int a = q / 50, m = q - a * 50;
            int loc = lo + a;
            const float* base = c2b + (size_t)loc * 200;
            bool ch = (a < chn);
            float ig = base[m]       + (ch ? msg[a][m]       : 0.0f);
            float og = base[50 + m]  + (ch ? msg[a][50 + m]  : 0.0f);
            float ug = base[100 + m] + (ch ? msg[a][100 + m] : 0.0f);
            float cn = fsig(ig) * ftanh(ug) + (ch ? fc_sum[loc][m] : 0.0f);
            float hn = base[150 + m] + fsig(og) * ftanh(cn);
            hcur[a][m] = hn;
            mcur[a][m] = cn;
            hfin[loc][m] = hn;
        }
        __syncthreads();

        if (tid < 250) {
            for (int a = tid / 50; a < A; a += 5) {
                float acc = fb;
                #pragma unroll
                for (int k4 = 0; k4 < 12; ++k4) {
                    float4 h4 = *(const float4*)&hcur[a][k4 * 4];
                    acc += fr[k4*4+0]*h4.x + fr[k4*4+1]*h4.y + fr[k4*4+2]*h4.z + fr[k4*4+3]*h4.w;
                }
                acc += fr[48]*hcur[a][48] + fr[49]*hcur[a][49];
                mcur[a][rF] = fsig(acc) * mcur[a][rF];
            }
        }
        __syncthreads();

        if (lvl > 0) {
            const int plo = (lo - 1) >> 1, phi = (hi - 1) >> 1;
            const int P = phi - plo + 1;
            for (int q = tid; q < P * 50; q += 256) {
                int pi = q / 50, m = q - pi * 50;
                int p = plo + pi;
                int c1 = 2 * p + 1, c2i = 2 * p + 2;
                float hs = hcur[c1 - lo][m];
                float fs = mcur[c1 - lo][m];
                if (c2i <= hi) { hs += hcur[c2i - lo][m]; fs += mcur[c2i - lo][m]; }
                h_sum[p][m] += hs;
                fc_sum[p][m] += fs;
            }
        }
        __syncthreads();
    }

    const float* tm = tmask + (size_t)b * 64;
    if (tid < 50) {
        float acc = 0.0f, ws = 0.0f;
        for (int l = 0; l < 64; ++l) {
            float wv = tm[l];
            ws += wv;
            acc += wv * hfin[l][tid];
        }
        float p = acc / ws;
        pool[tid] = p;
        out[3072 + (size_t)b * 50 + tid] = p;
    }
    __syncthreads();
    if (tid < 3) {
        float acc = Cb[tid];
        #pragma unroll
        for (int m = 0; m < 50; ++m) acc += Cw[tid * 50 + m] * pool[m];
        out[(size_t)b * 3 + tid] = acc;
    }
}

// ---------------------------------------------------------------------------
extern "C" void kernel_launch(void* const* d_in, const int* in_sizes, int n_in,
                              void* d_out, int out_size, void* d_ws, size_t ws_size,
                              hipStream_t stream) {
    (void)in_sizes; (void)n_in; (void)out_size; (void)ws_size;
    const int*   ids   = (const int*)d_in[0];
    const float* tmask = (const float*)d_in[3];
    const float* table = (const float*)d_in[5];
    const float* Wihf  = (const float*)d_in[6];
    const float* Whhf  = (const float*)d_in[7];
    const float* bf    = (const float*)d_in[8];
    const float* Wihb  = (const float*)d_in[9];
    const float* Whhb  = (const float*)d_in[10];
    const float* bb    = (const float*)d_in[11];
    const float* Wiou  = (const float*)d_in[12];
    const float* Uiouw = (const float*)d_in[13];
    const float* Uioub = (const float*)d_in[14];
    const float* biou  = (const float*)d_in[15];
    const float* Ufw   = (const float*)d_in[16];
    const float* Ufb   = (const float*)d_in[17];
    const float* Hw    = (const float*)d_in[18];
    const float* Hb    = (const float*)d_in[19];
    const float* Cw    = (const float*)d_in[20];
    const float* Cb    = (const float*)d_in[21];
    float* out = (float*)d_out;

    float* wsf = (float*)d_ws;
    float* xg = wsf;                                  // 65536*400 f32 (C2 later)
    float* x  = wsf + (size_t)65536 * 400;            // 65536*100 f32
    float* C2 = wsf;
    unsigned short* B1c = (unsigned short*)(wsf + 32768000);  // 10*2*4*448*8 ush
    unsigned short* B3c = (unsigned short*)(wsf + 32911360);  // 4*2*4*256*8 ush
    unsigned short* Whc = (unsigned short*)(wsf + 32944128);  // 2 * WHC_DIR ush

    // K0: all weight pre-conversions in ONE launch (25344 items)
    conv_fused<<<99, 256, 0, stream>>>(Wihf, Wihb, Wiou, Hw, Whhf, Whhb,
                                       B1c, B3c, Whc);
    // K1: xg = gather(embed)@[W_ih_f;W_ih_b]^T + bias   (N x 400)
    gemm_split<448, 10, 300, 400, true><<<1024, 256, 0, stream>>>(
        table, ids, B1c, bf, bb, 200, xg);
    // K2: MFMA BiLSTM -> x (N x 100) = [hf | hb]   (8 sents/block, 256 blocks)
    lstm_mfma<<<256, 256, 0, stream>>>(xg, Whc, x);
    // K3: C2 = x@[W_iou^T | H_w^T] + [b_iou | H_b]   (N x 200)
    gemm_split<256, 4, 100, 200, false><<<1024, 256, 0, stream>>>(
        x, nullptr, B3c, biou, Hb, 150, C2);
    // K4: TreeLSTM + pool + classifier
    tree_kernel<<<1024, 256, 0, stream>>>(
        C2, Uiouw, Uioub, Ufw, Ufb, tmask, Cw, Cb, out);
}